// Round 5
// baseline (20.602 us; speedup 1.0000x reference)
//
#include <hip/hip_runtime.h>
#include <hip/hip_bf16.h>

// Embedding gather: out[token, :] = weight[x[token], :]
// x: int32 [16384], weight: f32 [50257, 768], out: f32 [16384, 768]
// Software-pipelined: each wave owns 4 consecutive tokens; while storing
// token i's row (3x16B/lane) the 3 loads for token i+1 are already in
// flight -> chip sustains concurrent read+write streams instead of
// lockstep read-phase/write-phase.
// 1024 blocks x 256 thr = 4096 waves = 16 waves/CU.

typedef float f32x4 __attribute__((ext_vector_type(4)));

constexpr int TPW = 4;   // tokens per wave

__global__ void __launch_bounds__(256)
embed_gather_kernel(const int* __restrict__ x,
                    const f32x4* __restrict__ w,
                    f32x4* __restrict__ out,
                    int n_tokens) {
    const int wave = threadIdx.x >> 6;     // 0..3
    const int lane = threadIdx.x & 63;
    const int wid  = blockIdx.x * 4 + wave;
    int t = wid * TPW;
    if (t >= n_tokens) return;

    // Prologue: issue loads for the first token.
    int row = x[t];
    const f32x4* __restrict__ s = w + (size_t)row * 192;
    f32x4 a = s[lane], b = s[lane + 64], c = s[lane + 128];

    #pragma unroll
    for (int i = 0; i < TPW; ++i) {
        f32x4 a2, b2, c2;
        if (i + 1 < TPW && t + 1 < n_tokens) {
            // Prefetch next token's row before draining current stores.
            const int row2 = x[t + 1];
            const f32x4* __restrict__ s2 = w + (size_t)row2 * 192;
            a2 = s2[lane];
            b2 = s2[lane + 64];
            c2 = s2[lane + 128];
        }
        f32x4* __restrict__ dst = out + (size_t)t * 192;
        __builtin_nontemporal_store(a, &dst[lane]);
        __builtin_nontemporal_store(b, &dst[lane + 64]);
        __builtin_nontemporal_store(c, &dst[lane + 128]);
        a = a2; b = b2; c = c2;
        ++t;
        if (t >= n_tokens) return;
    }
}

extern "C" void kernel_launch(void* const* d_in, const int* in_sizes, int n_in,
                              void* d_out, int out_size, void* d_ws, size_t ws_size,
                              hipStream_t stream) {
    const int* x = (const int*)d_in[0];
    const float* weight = (const float*)d_in[1];
    float* out = (float*)d_out;

    const int n_tokens = in_sizes[0];          // 16384
    const int n_waves  = (n_tokens + TPW - 1) / TPW;   // 4096
    const int blocks   = (n_waves + 3) / 4;            // 1024
    embed_gather_kernel<<<blocks, 256, 0, stream>>>(
        x, (const f32x4*)weight, (f32x4*)out, n_tokens);
}